// Round 1
// baseline (234.683 us; speedup 1.0000x reference)
//
#include <hip/hip_runtime.h>

// HolomorphicHealingBackprop: df is trivially 4.0 everywhere, so
// alpha = tanh(4) is a constant and mask == 1. Per quaternion q = (w,x,y,z):
//   h = normalize_eps( (t*w + a, -t*x, -t*y, -t*z) ),  t = 1 - a
//   out = normalize_eps( q (Hamilton) h )
// Pure streaming kernel: 16 B in / 16 B out per quaternion -> HBM-bound.
// Roofline: 268.4 MB total @ ~6.7 TB/s achievable = ~40 us.
//
// This revision: grid-stride with capped grid (2048 blocks = 8/CU), exact
// 16-iteration main loop unrolled x4 for load-level parallelism, generic
// tail. Arithmetic bit-identical to the previous (passing) version.

#define ALPHA_T 0.9993292997390670f  // tanh(4.0)

__device__ __forceinline__ float4 heal_one(float4 q) {
  const float a = ALPHA_T;
  const float t = 1.0f - a;

  // correction * conj_sign
  float h0 = t * q.x + a;
  float h1 = -t * q.y;
  float h2 = -t * q.z;
  float h3 = -t * q.w;

  // normalize with +1e-8 (matches reference EPS)
  float n1 = sqrtf(h0 * h0 + h1 * h1 + h2 * h2 + h3 * h3);
  float inv1 = 1.0f / (n1 + 1e-8f);
  h0 *= inv1; h1 *= inv1; h2 *= inv1; h3 *= inv1;

  // Hamilton product q * h, q = (q.x, q.y, q.z, q.w) as (w,x,y,z)
  float ow = q.x * h0 - q.y * h1 - q.z * h2 - q.w * h3;
  float ox = q.x * h1 + q.y * h0 + q.z * h3 - q.w * h2;
  float oy = q.x * h2 - q.y * h3 + q.z * h0 + q.w * h1;
  float oz = q.x * h3 + q.y * h2 - q.z * h1 + q.w * h0;

  // final normalize with +1e-8
  float n2 = sqrtf(ow * ow + ox * ox + oy * oy + oz * oz);
  float inv2 = 1.0f / (n2 + 1e-8f);

  return make_float4(ow * inv2, ox * inv2, oy * inv2, oz * inv2);
}

__global__ __launch_bounds__(256) void heal_kernel(
    const float4* __restrict__ xin, float4* __restrict__ out,
    int n_quat, int iters) {
  const int tid = blockIdx.x * blockDim.x + threadIdx.x;
  const int stride = gridDim.x * blockDim.x;

  // Exact-cover main loop: no per-iteration bounds check; unroll for MLP.
  int i = tid;
#pragma unroll 4
  for (int k = 0; k < iters; ++k, i += stride) {
    out[i] = heal_one(xin[i]);
  }
  // Tail (no-op when stride divides n_quat, as in the bench shape).
  if (i < n_quat) {
    out[i] = heal_one(xin[i]);
  }
}

extern "C" void kernel_launch(void* const* d_in, const int* in_sizes, int n_in,
                              void* d_out, int out_size, void* d_ws, size_t ws_size,
                              hipStream_t stream) {
  const float4* x = (const float4*)d_in[0];
  float4* out = (float4*)d_out;
  int n_quat = in_sizes[0] / 4;  // 8,388,608 quaternions

  const int block = 256;
  int grid = (n_quat + block - 1) / block;
  if (grid > 2048) grid = 2048;          // 8 blocks/CU on 256 CUs
  const int stride = grid * block;
  const int iters = n_quat / stride;     // 16 for the bench shape

  heal_kernel<<<grid, block, 0, stream>>>(x, out, n_quat, iters);
}

// Round 2
// 223.471 us; speedup vs baseline: 1.0502x; 1.0502x over previous
//
#include <hip/hip_runtime.h>

// HolomorphicHealingBackprop: df is trivially 4.0 everywhere, so
// alpha = tanh(4) is a constant and mask == 1. Per quaternion q = (w,x,y,z):
//   h = normalize_eps( (t*w + a, -t*x, -t*y, -t*z) ),  t = 1 - a
//   out = normalize_eps( q (Hamilton) h )
// Pure streaming kernel: 16 B in / 16 B out per quaternion -> HBM-bound.
//
// R1 post-mortem: capped-grid grid-stride was LATENCY-bound (VALUBusy 23%,
// 3.3 TB/s logical, VGPR=24 -> no cross-iteration load pipelining). Revert
// to max-TLP: flat grid, 2 elements/thread (split-half pattern, both loads
// independent + perfectly coalesced). Input (134 MB) fits L3 (FETCH showed
// only half coming from HBM) -> use NON-TEMPORAL stores so the output
// stream doesn't evict the input from L3; reads then come at L3 bandwidth.

#define ALPHA_T 0.9993292997390670f  // tanh(4.0)

typedef float f32x4 __attribute__((ext_vector_type(4)));

__device__ __forceinline__ f32x4 heal_one(f32x4 q) {
  const float a = ALPHA_T;
  const float t = 1.0f - a;

  // correction * conj_sign   (q = (w,x,y,z) in lanes 0..3)
  float h0 = t * q.x + a;
  float h1 = -t * q.y;
  float h2 = -t * q.z;
  float h3 = -t * q.w;

  // normalize with +1e-8 (matches reference EPS)
  float n1 = sqrtf(h0 * h0 + h1 * h1 + h2 * h2 + h3 * h3);
  float inv1 = 1.0f / (n1 + 1e-8f);
  h0 *= inv1; h1 *= inv1; h2 *= inv1; h3 *= inv1;

  // Hamilton product q * h
  float ow = q.x * h0 - q.y * h1 - q.z * h2 - q.w * h3;
  float ox = q.x * h1 + q.y * h0 + q.z * h3 - q.w * h2;
  float oy = q.x * h2 - q.y * h3 + q.z * h0 + q.w * h1;
  float oz = q.x * h3 + q.y * h2 - q.z * h1 + q.w * h0;

  // final normalize with +1e-8
  float n2 = sqrtf(ow * ow + ox * ox + oy * oy + oz * oz);
  float inv2 = 1.0f / (n2 + 1e-8f);

  f32x4 r;
  r.x = ow * inv2; r.y = ox * inv2; r.z = oy * inv2; r.w = oz * inv2;
  return r;
}

__global__ __launch_bounds__(256) void heal_kernel(
    const f32x4* __restrict__ xin, f32x4* __restrict__ out,
    int n_quat, int half) {
  const int i0 = blockIdx.x * blockDim.x + threadIdx.x;
  if (i0 >= half) return;
  const int i1 = i0 + half;

  // Two independent loads in flight; both instructions perfectly coalesced
  // (lane i -> base + i*16B).
  f32x4 q0 = xin[i0];
  if (i1 < n_quat) {
    f32x4 q1 = xin[i1];
    f32x4 r0 = heal_one(q0);
    f32x4 r1 = heal_one(q1);
    __builtin_nontemporal_store(r0, &out[i0]);
    __builtin_nontemporal_store(r1, &out[i1]);
  } else {
    f32x4 r0 = heal_one(q0);
    __builtin_nontemporal_store(r0, &out[i0]);
  }
}

extern "C" void kernel_launch(void* const* d_in, const int* in_sizes, int n_in,
                              void* d_out, int out_size, void* d_ws, size_t ws_size,
                              hipStream_t stream) {
  const f32x4* x = (const f32x4*)d_in[0];
  f32x4* out = (f32x4*)d_out;
  int n_quat = in_sizes[0] / 4;      // 8,388,608 quaternions
  int half = (n_quat + 1) / 2;       // elements handled in the first wave of loads

  const int block = 256;
  int grid = (half + block - 1) / block;   // 16384 blocks @ bench shape
  heal_kernel<<<grid, block, 0, stream>>>(x, out, n_quat, half);
}

// Round 3
// 221.336 us; speedup vs baseline: 1.0603x; 1.0096x over previous
//
#include <hip/hip_runtime.h>

// HolomorphicHealingBackprop — closed form.
//
// df = 4.0 everywhere -> alpha a = tanh(4), t = 1-a, mask = 1.
// Reference: h = normalize(t*conj(q) + a*e0); out = normalize(q (x) h).
// Both normalizes are scale-invariant, and q (x) conj(q) = |q|^2 * e0, so:
//     q (x) h_raw = t*|q|^2*e0 + a*q
//     out = normalize( (w + C*S, x, y, z) ),  S = |q|^2,  C = t/a
// 14 VALU ops/quat (was ~70 with 2 precise sqrt + 2 precise div) -> the
// wave math chain (~140 cy) no longer co-limits the 6.3 TB/s stream
// (budget ~204 cy/wave at copy BW).
//
// Memory structure: exact R0 revert (best measured): flat grid, one
// float4 per thread, regular coalesced stores.
// Error vs reference: eps-term ~1e-8 rel + v_rsq_f32 ~1e-7 rel, far
// below the harness absmax of 2^-8.

#define C_TA 6.7115040148e-4f  // (1 - tanh(4)) / tanh(4)

typedef float f32x4 __attribute__((ext_vector_type(4)));

__global__ __launch_bounds__(256) void heal_kernel(
    const f32x4* __restrict__ xin, f32x4* __restrict__ out, int n_quat) {
  int i = blockIdx.x * blockDim.x + threadIdx.x;
  if (i >= n_quat) return;

  f32x4 q = xin[i];  // (w, x, y, z) in lanes 0..3

  float S = q.x * q.x + q.y * q.y + q.z * q.z + q.w * q.w;
  float pw = __builtin_fmaf(C_TA, S, q.x);  // w + C*S

  float d = pw * pw + q.y * q.y + q.z * q.z + q.w * q.w;
  float inv = __builtin_amdgcn_rsqf(d);     // v_rsq_f32

  f32x4 r;
  r.x = pw * inv;
  r.y = q.y * inv;
  r.z = q.z * inv;
  r.w = q.w * inv;
  out[i] = r;
}

extern "C" void kernel_launch(void* const* d_in, const int* in_sizes, int n_in,
                              void* d_out, int out_size, void* d_ws, size_t ws_size,
                              hipStream_t stream) {
  const f32x4* x = (const f32x4*)d_in[0];
  f32x4* out = (f32x4*)d_out;
  int n_quat = in_sizes[0] / 4;  // 8,388,608 quaternions

  const int block = 256;
  int grid = (n_quat + block - 1) / block;  // 32768 blocks
  heal_kernel<<<grid, block, 0, stream>>>(x, out, n_quat);
}